// Round 5
// baseline (716.574 us; speedup 1.0000x reference)
//
#include <hip/hip_runtime.h>

#define B_ 4
#define N_ 16384
#define DIN_ 512
#define H_ 8
#define DH_ 64
#define M_ 32
#define HM_ 256
#define INNER_ 512
#define NSPLIT 32   // K2 n-split = number of S partials

typedef _Float16 fp16_t;
typedef _Float16 h8 __attribute__((ext_vector_type(8)));
typedef _Float16 h4 __attribute__((ext_vector_type(4)));
typedef float f4 __attribute__((ext_vector_type(4)));

// Fragment-blocked operand layout (16 rows x 32 contraction per tile = 512 fp16):
// element (row, k) lives at lane*8+e with lane=(k%32/8)*16+row%16, e=k%8.
// One wave loads a fragment as a single coalesced h8 (1 KB) -- no LDS, no barriers.

// ---------------- K0: Wcomp_blk[q=4][kt=16][c=4][512] = (Wslice@Wx_h)/temp ----------
__global__ __launch_bounds__(256) void k0_prep(
    const float* __restrict__ Wx, const float* __restrict__ bx,
    const float* __restrict__ Wslice, const float* __restrict__ bslice,
    const float* __restrict__ temperature,
    fp16_t* __restrict__ Wcomp_blk, float* __restrict__ bcomp) {
  __shared__ float ws[M_ * DH_];
  const int h = blockIdx.x;
  const int tid = threadIdx.x;
  for (int i = tid; i < M_ * DH_; i += 256) ws[i] = Wslice[i];
  __syncthreads();
  const float invt = 1.0f / temperature[h];
  const int q = h >> 1, cb = (h & 1) * 2;
  for (int j = 0; j < 8; ++j) {
    const int idx = tid + j * 256;            // 0..2047
    const int lane = idx & 63;
    const int c = cb + ((idx >> 6) & 1);
    const int kt = idx >> 7;                  // 0..15
    const int m = ((c & 1) * 16) + (lane & 15);
    const int k0 = kt * 32 + (lane >> 4) * 8;
    float acc[8] = {};
    for (int d = 0; d < DH_; ++d) {
      const float wsm = ws[m * DH_ + d];
      const float* wx = Wx + (size_t)(h * DH_ + d) * DIN_ + k0;
      f4 a = *(const f4*)wx;
      f4 bb = *(const f4*)(wx + 4);
      acc[0] += wsm * a.x;  acc[1] += wsm * a.y;
      acc[2] += wsm * a.z;  acc[3] += wsm * a.w;
      acc[4] += wsm * bb.x; acc[5] += wsm * bb.y;
      acc[6] += wsm * bb.z; acc[7] += wsm * bb.w;
    }
    h8 o;
    #pragma unroll
    for (int e = 0; e < 8; ++e) o[e] = (fp16_t)(acc[e] * invt);
    *(h8*)(Wcomp_blk + (((size_t)(q * 16 + kt) * 4 + c) * 512) + lane * 8) = o;
  }
  if (tid < M_) {
    const int m = tid;
    float acc = bslice[m];
    for (int d = 0; d < DH_; ++d) acc += ws[m * DH_ + d] * bx[h * DH_ + d];
    bcomp[h * M_ + m] = acc * invt;
  }
}

// ---------------- K_xt: x [b][n][k] fp32 -> xt_blk [b][kt=32][nc=N/32][512] fp16 ----
// block: 64 n x 512 k. LDS transposed tile [512 k][stride 66].
__global__ __launch_bounds__(512) void k_xt(
    const float* __restrict__ x, fp16_t* __restrict__ xt_blk) {
  __shared__ fp16_t lxt[512 * 66];    // 67584 B
  const int tid = threadIdx.x;
  const int n0 = blockIdx.x * 64;
  const int b = blockIdx.y;
  const float* xb = x + ((size_t)b * N_ + n0) * DIN_;
  #pragma unroll
  for (int i = 0; i < 16; ++i) {
    const int id = tid + i * 512;     // 0..8191 = 64 n x 128 f4-chunks
    const int n = id >> 7;            // 0..63
    const int kc = id & 127;          // 0..127
    f4 v = *(const f4*)(xb + (size_t)n * DIN_ + kc * 4);
    lxt[(kc * 4 + 0) * 66 + n] = (fp16_t)v.x;
    lxt[(kc * 4 + 1) * 66 + n] = (fp16_t)v.y;
    lxt[(kc * 4 + 2) * 66 + n] = (fp16_t)v.z;
    lxt[(kc * 4 + 3) * 66 + n] = (fp16_t)v.w;
  }
  __syncthreads();
  const int lane = tid & 63, wv = tid >> 6;
  #pragma unroll
  for (int f = 0; f < 8; ++f) {
    const int frag = wv * 8 + f;      // 0..63 = 32 kt x 2 nc
    const int kt = frag >> 1, ncl = frag & 1;
    const int k_l = kt * 16 + (lane & 15);
    const int nb = ncl * 32 + (lane >> 4) * 8;
    h8 v;
    #pragma unroll
    for (int e = 0; e < 8; ++e) v[e] = lxt[k_l * 66 + nb + e];
    *(h8*)(xt_blk + (((size_t)(b * 32 + kt) * (N_ / 32)) + (n0 >> 5) + ncl) * 512 + lane * 8) = v;
  }
}

// ---------------- K1: logits GEMM (barrier-free K-loop) + softmax + w/wt emits ------
// block: 256 n x 64 hm (hm-quarter q), 512 threads, Wcomp quarter LDS-resident
__global__ __launch_bounds__(512) void k1_logits(
    const float* __restrict__ x, const fp16_t* __restrict__ Wcomp_blk,
    const float* __restrict__ bcomp, fp16_t* __restrict__ w_blk,
    fp16_t* __restrict__ wt_blk) {
  __shared__ __align__(16) fp16_t smem[32768];   // 64 KB: Wcomp quarter, then lt tile
  const int tid = threadIdx.x, lane = tid & 63, wv = tid >> 6;
  const int n0 = blockIdx.x * 256;
  const int q = blockIdx.y;
  const int b = blockIdx.z;
  // one-time Wcomp quarter load (frag-blocked, coalesced)
  {
    const fp16_t* src = Wcomp_blk + (size_t)q * 32768;
    #pragma unroll
    for (int j = 0; j < 8; ++j) {
      const int idx = tid + j * 512;
      *(h8*)&smem[idx * 8] = *(const h8*)(src + (size_t)idx * 8);
    }
  }
  __syncthreads();
  f4 acc[2][4] = {};
  const float* xp = x + ((size_t)b * N_ + n0 + wv * 32 + (lane & 15)) * DIN_ + (lane >> 4) * 8;
  #pragma unroll 4
  for (int kt = 0; kt < 16; ++kt) {
    h8 af[2];
    #pragma unroll
    for (int tn = 0; tn < 2; ++tn) {
      f4 v0 = *(const f4*)(xp + (size_t)tn * 16 * DIN_ + kt * 32);
      f4 v1 = *(const f4*)(xp + (size_t)tn * 16 * DIN_ + kt * 32 + 4);
      af[tn] = h8{(fp16_t)v0.x, (fp16_t)v0.y, (fp16_t)v0.z, (fp16_t)v0.w,
                  (fp16_t)v1.x, (fp16_t)v1.y, (fp16_t)v1.z, (fp16_t)v1.w};
    }
    h8 bf[4];
    #pragma unroll
    for (int c = 0; c < 4; ++c)
      bf[c] = *(const h8*)&smem[(kt * 4 + c) * 512 + lane * 8];
    #pragma unroll
    for (int tn = 0; tn < 2; ++tn)
      #pragma unroll
      for (int c = 0; c < 4; ++c)
        acc[tn][c] = __builtin_amdgcn_mfma_f32_16x16x32_f16(af[tn], bf[c], acc[tn][c], 0, 0, 0);
  }
  __syncthreads();   // Wcomp dead; smem becomes lt [256 n][72] swizzled

  // bias-add + dump logits to lt
  float bc[4];
  #pragma unroll
  for (int c = 0; c < 4; ++c) bc[c] = bcomp[q * 64 + c * 16 + (lane & 15)];
  const int rg = (lane >> 4) * 4;
  #pragma unroll
  for (int tn = 0; tn < 2; ++tn)
    #pragma unroll
    for (int c = 0; c < 4; ++c)
      #pragma unroll
      for (int r = 0; r < 4; ++r) {
        const int n_l = wv * 32 + tn * 16 + rg + r;
        const int hm_l = c * 16 + (lane & 15);
        const int sg = (hm_l >> 3) ^ ((n_l >> 3) & 7);
        smem[n_l * 72 + sg * 8 + (hm_l & 7)] = (fp16_t)(acc[tn][c][r] + bc[c]);
      }
  __syncthreads();

  // softmax: thread -> one (n, head) row of 32
  {
    const int n_l = tid >> 1, h_l = tid & 1;
    const int sw = (n_l >> 3) & 7;
    h8 ch[4];
    #pragma unroll
    for (int g = 0; g < 4; ++g)
      ch[g] = *(const h8*)&smem[n_l * 72 + ((h_l * 4 + g) ^ sw) * 8];
    float v[32];
    #pragma unroll
    for (int g = 0; g < 4; ++g)
      #pragma unroll
      for (int e = 0; e < 8; ++e) v[g * 8 + e] = (float)ch[g][e];
    float mx = v[0];
    #pragma unroll
    for (int j = 1; j < 32; ++j) mx = fmaxf(mx, v[j]);
    float sm = 0.f;
    #pragma unroll
    for (int j = 0; j < 32; ++j) { v[j] = __expf(v[j] - mx); sm += v[j]; }
    const float inv = __builtin_amdgcn_rcpf(sm);
    #pragma unroll
    for (int g = 0; g < 4; ++g) {
      h8 oc;
      #pragma unroll
      for (int e = 0; e < 8; ++e) oc[e] = (fp16_t)(v[g * 8 + e] * inv);
      *(h8*)&smem[n_l * 72 + ((h_l * 4 + g) ^ sw) * 8] = oc;
    }
  }
  __syncthreads();

  // w_blk emit (K4-A layout [b][nt][hmb=8][512]): 32 frags, 4 per wave
  #pragma unroll
  for (int f = 0; f < 4; ++f) {
    const int frag = wv * 4 + f;          // 0..31 = 16 nt x 2 hmb
    const int nt_l = frag >> 1, hmb_l = frag & 1;
    const int n_l = nt_l * 16 + (lane & 15);
    const int g = hmb_l * 4 + (lane >> 4);
    const int sw = (n_l >> 3) & 7;
    h8 v = *(const h8*)&smem[n_l * 72 + (g ^ sw) * 8];
    *(h8*)(w_blk + (((size_t)(b * (N_ / 16) + (n0 >> 4) + nt_l) * 8) + q * 2 + hmb_l) * 512 + lane * 8) = v;
  }
  // wt_blk emit (K2-A layout [b][hmt=16][nc][512]): 32 frags, 4 per wave
  #pragma unroll
  for (int f = 0; f < 4; ++f) {
    const int frag = wv * 4 + f;          // 0..31 = 4 hmt x 8 nc
    const int hmt_l = frag >> 3, nc_l = frag & 7;
    const int hm_l = hmt_l * 16 + (lane & 15);
    const int nb = nc_l * 32 + (lane >> 4) * 8;
    h8 v;
    #pragma unroll
    for (int e = 0; e < 8; ++e) {
      const int n_l = nb + e;
      v[e] = smem[n_l * 72 + (((hm_l >> 3) ^ ((n_l >> 3) & 7)) * 8) + (hm_l & 7)];
    }
    *(h8*)(wt_blk + (((size_t)(b * 16 + q * 4 + hmt_l) * (N_ / 32)) + (n0 >> 5) + nc_l) * 512 + lane * 8) = v;
  }
}

// ---------------- K2: S_p[gy][b][hm][k] (fp16 partials, no atomics) -----------------
__global__ __launch_bounds__(256) void k2_S(
    const fp16_t* __restrict__ wt_blk, const fp16_t* __restrict__ xt_blk,
    fp16_t* __restrict__ S_p, float* __restrict__ norm) {
  const int tid = threadIdx.x, lane = tid & 63, wv = tid >> 6;
  const int hm0 = (blockIdx.x & 1) * 128;
  const int kc0 = (blockIdx.x >> 1) * 128;
  const int gy = blockIdx.y;
  const int nt0 = gy * 16;                    // 512 n = 16 n-tiles of 32
  const int b = blockIdx.z;
  const int hmw = (wv & 1) * 64, kw = (wv >> 1) * 64;
  const int hmt0 = (hm0 + hmw) >> 4;
  const int kt0 = (kc0 + kw) >> 4;
  const fp16_t* ap = wt_blk + (((size_t)(b * 16 + hmt0)) * (N_ / 32) + nt0) * 512 + lane * 8;
  const fp16_t* bp = xt_blk + (((size_t)(b * 32 + kt0)) * (N_ / 32) + nt0) * 512 + lane * 8;
  const size_t arow = (size_t)(N_ / 32) * 512;
  f4 acc[4][4] = {};
  float ns[4] = {0.f, 0.f, 0.f, 0.f};
  const bool do_norm = (kc0 == 0) && (kw == 0);

  for (int it = 0; it < 16; ++it) {
    h8 af[4], bf[4];
    #pragma unroll
    for (int t = 0; t < 4; ++t) af[t] = *(const h8*)(ap + (size_t)t * arow + it * 512);
    #pragma unroll
    for (int t = 0; t < 4; ++t) bf[t] = *(const h8*)(bp + (size_t)t * arow + it * 512);
    #pragma unroll
    for (int tn = 0; tn < 4; ++tn)
      #pragma unroll
      for (int tc = 0; tc < 4; ++tc)
        acc[tn][tc] = __builtin_amdgcn_mfma_f32_16x16x32_f16(af[tn], bf[tc], acc[tn][tc], 0, 0, 0);
    if (do_norm) {
      #pragma unroll
      for (int t = 0; t < 4; ++t)
        #pragma unroll
        for (int e = 0; e < 8; ++e) ns[t] += (float)af[t][e];
    }
  }
  if (do_norm) {
    #pragma unroll
    for (int t = 0; t < 4; ++t) {
      ns[t] += __shfl_xor(ns[t], 16);
      ns[t] += __shfl_xor(ns[t], 32);
    }
    if (lane < 16) {
      #pragma unroll
      for (int t = 0; t < 4; ++t)
        atomicAdd(&norm[b * HM_ + (hmt0 + t) * 16 + lane], ns[t]);
    }
  }
  fp16_t* sp = S_p + ((size_t)(gy * B_ + b)) * HM_ * DIN_;
  const int rg = (lane >> 4) * 4;
  #pragma unroll
  for (int tn = 0; tn < 4; ++tn)
    #pragma unroll
    for (int tc = 0; tc < 4; ++tc)
      #pragma unroll
      for (int r = 0; r < 4; ++r) {
        const int hm = hm0 + hmw + tn * 16 + rg + r;
        const int k = kc0 + kw + tc * 16 + (lane & 15);
        sp[(size_t)hm * DIN_ + k] = (fp16_t)acc[tn][tc][r];
      }
}

// ---------------- K2r: S = sum_p S_p  (32 fp16 partials -> fp32) --------------------
__global__ __launch_bounds__(256) void k2r(
    const fp16_t* __restrict__ S_p, float* __restrict__ S) {
  const size_t idx = (size_t)blockIdx.x * 256 + threadIdx.x;  // 65536 h8-chunks
  float s[8] = {};
  #pragma unroll 8
  for (int p = 0; p < NSPLIT; ++p) {
    h8 v = *(const h8*)(S_p + (size_t)p * B_ * HM_ * DIN_ + idx * 8);
    #pragma unroll
    for (int e = 0; e < 8; ++e) s[e] += (float)v[e];
  }
  f4 o0 = {s[0], s[1], s[2], s[3]}, o1 = {s[4], s[5], s[6], s[7]};
  *(f4*)(S + idx * 8) = o0;
  *(f4*)(S + idx * 8 + 4) = o1;
}

// ---------------- K3a: slice_token[b,h,m,d] = (S.Wfx + bfx*norm)/(norm+1e-5) --------
__global__ __launch_bounds__(256) void k3a_st(
    const float* __restrict__ S, const float* __restrict__ Wfx,
    const float* __restrict__ bfx, const float* __restrict__ norm,
    float* __restrict__ st) {
  const int mq = blockIdx.x;
  const int h = blockIdx.y;
  const int b = blockIdx.z;
  const int tid = threadIdx.x;
  const int m = mq * 4 + (tid >> 6);
  const int d = tid & 63;
  const float* sr = S + ((size_t)b * HM_ + h * M_ + m) * DIN_;
  const float* wr = Wfx + (size_t)(h * DH_ + d) * DIN_;
  float acc = 0.f;
  #pragma unroll 8
  for (int k = 0; k < DIN_; k += 4) {
    f4 a = *(const f4*)(sr + k);
    f4 bb = *(const f4*)(wr + k);
    acc += a.x * bb.x + a.y * bb.y + a.z * bb.z + a.w * bb.w;
  }
  const float nr = norm[b * HM_ + h * M_ + m];
  st[(((size_t)b * H_ + h) * M_ + m) * DH_ + d] =
      (acc + bfx[h * DH_ + d] * nr) / (nr + 1e-5f);
}

// ---------------- K3b: tiny M=32 attention per (b,h) --------------------------------
__global__ __launch_bounds__(256) void k3b_attn(
    const float* __restrict__ st_g, const float* __restrict__ Wq,
    const float* __restrict__ Wk, const float* __restrict__ Wv,
    float* __restrict__ os_g) {
  __shared__ float st[32][65], qs[32][65], ks[32][65], vs[32][65], at[32][33];
  const int h = blockIdx.x, b = blockIdx.y, tid = threadIdx.x;
  const float* stp = st_g + ((size_t)b * H_ + h) * M_ * DH_;
  for (int i = tid; i < 2048; i += 256) st[i >> 6][i & 63] = stp[i];
  __syncthreads();
  for (int i = tid; i < 2048; i += 256) {
    const int m = i >> 6, d = i & 63;
    float aq = 0, ak = 0, av = 0;
    #pragma unroll 8
    for (int dd = 0; dd < 64; ++dd) {
      const float s = st[m][dd];
      aq += s * Wq[d * 64 + dd];
      ak += s * Wk[d * 64 + dd];
      av += s * Wv[d * 64 + dd];
    }
    qs[m][d] = aq; ks[m][d] = ak; vs[m][d] = av;
  }
  __syncthreads();
  for (int i = tid; i < 1024; i += 256) {
    const int m = i >> 5, j = i & 31;
    float a = 0;
    #pragma unroll 8
    for (int d = 0; d < 64; ++d) a += qs[m][d] * ks[j][d];
    at[m][j] = a * 0.125f;
  }
  __syncthreads();
  if (tid < 32) {
    const int m = tid;
    float mx = -1e30f;
    for (int j = 0; j < 32; ++j) mx = fmaxf(mx, at[m][j]);
    float sm = 0;
    for (int j = 0; j < 32; ++j) { const float e = __expf(at[m][j] - mx); at[m][j] = e; sm += e; }
    const float inv = 1.0f / sm;
    for (int j = 0; j < 32; ++j) at[m][j] *= inv;
  }
  __syncthreads();
  float* osp = os_g + ((size_t)b * H_ + h) * M_ * DH_;
  for (int i = tid; i < 2048; i += 256) {
    const int m = i >> 6, d = i & 63;
    float a = 0;
    #pragma unroll 8
    for (int j = 0; j < 32; ++j) a += at[m][j] * vs[j][d];
    osp[i] = a;
  }
}

// ---------------- K3c: Ct_blk[b][kkt=32][hmb=8][512]  (K4 B-operand layout) ---------
__global__ __launch_bounds__(256) void k3c_ct(
    const float* __restrict__ os_g, const float* __restrict__ Wout,
    fp16_t* __restrict__ Ct_blk) {
  const int tid = threadIdx.x, lane = tid & 63, wv = tid >> 6;
  const int b = blockIdx.y;
  const int ti = blockIdx.x * 4 + wv;     // 0..255 tiles
  const int kkt = ti >> 3, hmb = ti & 7;
  const int kk = kkt * 16 + (lane & 15);
  h8 outv;
  #pragma unroll
  for (int e = 0; e < 8; ++e) {
    const int hm = hmb * 32 + (lane >> 4) * 8 + e;
    const int h = hm >> 5, m = hm & 31;
    const float* op = os_g + (((size_t)b * H_ + h) * M_ + m) * DH_;
    const float* wp = Wout + (size_t)kk * INNER_ + h * DH_;
    float acc = 0.f;
    #pragma unroll
    for (int d = 0; d < 64; d += 4) {
      f4 a = *(const f4*)(op + d);
      f4 w4 = *(const f4*)(wp + d);
      acc += a.x * w4.x + a.y * w4.y + a.z * w4.z + a.w * w4.w;
    }
    outv[e] = (fp16_t)acc;
  }
  *(h8*)(Ct_blk + (((size_t)(b * 32 + kkt)) * 8 + hmb) * 512 + lane * 8) = outv;
}

// ---------------- K4: out = w . Ct^T + bout — barrier-free streaming MFMA -----------
__global__ __launch_bounds__(256) void k4_out(
    const fp16_t* __restrict__ w_blk, const fp16_t* __restrict__ Ct_blk,
    const float* __restrict__ bout, float* __restrict__ out) {
  const int tid = threadIdx.x, lane = tid & 63, wv = tid >> 6;
  const int kk0 = blockIdx.x * 128;
  const int n0 = blockIdx.y * 128;
  const int b = blockIdx.z;
  const int nh = (wv & 1) * 64, kh = (wv >> 1) * 64;
  const int nt0 = (n0 + nh) >> 4;
  const int kkt0 = (kk0 + kh) >> 4;
  const fp16_t* ap = w_blk + ((size_t)(b * (N_ / 16) + nt0)) * 8 * 512 + lane * 8;
  const fp16_t* bp = Ct_blk + ((size_t)(b * 32 + kkt0)) * 8 * 512 + lane * 8;
  f4 acc[4][4] = {};

  #pragma unroll
  for (int hmb = 0; hmb < 8; ++hmb) {
    h8 af[4], bf[4];
    #pragma unroll
    for (int t = 0; t < 4; ++t) af[t] = *(const h8*)(ap + (size_t)t * 8 * 512 + hmb * 512);
    #pragma unroll
    for (int t = 0; t < 4; ++t) bf[t] = *(const h8*)(bp + (size_t)t * 8 * 512 + hmb * 512);
    #pragma unroll
    for (int tn = 0; tn < 4; ++tn)
      #pragma unroll
      for (int tc = 0; tc < 4; ++tc)
        acc[tn][tc] = __builtin_amdgcn_mfma_f32_16x16x32_f16(af[tn], bf[tc], acc[tn][tc], 0, 0, 0);
  }
  const int rg = (lane >> 4) * 4;
  #pragma unroll
  for (int tc = 0; tc < 4; ++tc) {
    const int kk = kk0 + kh + tc * 16 + (lane & 15);
    const float bo = bout[kk];
    #pragma unroll
    for (int tn = 0; tn < 4; ++tn)
      #pragma unroll
      for (int r = 0; r < 4; ++r) {
        const int n = n0 + nh + tn * 16 + rg + r;
        out[((size_t)b * N_ + n) * DIN_ + kk] = acc[tn][tc][r] + bo;
      }
  }
}

extern "C" void kernel_launch(void* const* d_in, const int* in_sizes, int n_in,
                              void* d_out, int out_size, void* d_ws, size_t ws_size,
                              hipStream_t stream) {
  (void)in_sizes; (void)n_in; (void)out_size; (void)ws_size;
  const float* x       = (const float*)d_in[0];
  const float* Wx      = (const float*)d_in[1];
  const float* bx      = (const float*)d_in[2];
  const float* Wfx     = (const float*)d_in[3];
  const float* bfx     = (const float*)d_in[4];
  const float* Wslice  = (const float*)d_in[5];
  const float* bslice  = (const float*)d_in[6];
  const float* Wq      = (const float*)d_in[7];
  const float* Wk      = (const float*)d_in[8];
  const float* Wv      = (const float*)d_in[9];
  const float* Wout    = (const float*)d_in[10];
  const float* bout    = (const float*)d_in[11];
  const float* temp    = (const float*)d_in[12];
  float* out = (float*)d_out;

  char* ws = (char*)d_ws;
  fp16_t* w_blk  = (fp16_t*)ws;                    //  33,554,432 : w blocked (K4-A)
  fp16_t* wt_blk = (fp16_t*)(ws + 33554432);       //  33,554,432 : w^T blocked (K2-A)
  fp16_t* xt_blk = (fp16_t*)(ws + 67108864);       //  67,108,864 : x^T fp16 blocked (K2-B)
  fp16_t* S_p    = (fp16_t*)(ws + 134217728);      //  33,554,432 : 32 fp16 S partials
  float*  S      = (float*)(ws + 167772160);       //   2,097,152
  float*  norm   = (float*)(ws + 169869312);       //       4,096
  float*  st     = (float*)(ws + 169873408);       //     262,144
  float*  os     = (float*)(ws + 170135552);       //     262,144
  fp16_t* Ct_blk = (fp16_t*)(ws + 170397696);      //   1,048,576
  fp16_t* Wcomp  = (fp16_t*)(ws + 171446272);      //     262,144
  float*  bcomp  = (float*)(ws + 171708416);       //       1,024

  hipMemsetAsync(norm, 0, (size_t)B_ * HM_ * 4, stream);
  k0_prep<<<dim3(H_), 256, 0, stream>>>(Wx, bx, Wslice, bslice, temp, Wcomp, bcomp);
  k_xt<<<dim3(N_ / 64, B_), 512, 0, stream>>>(x, xt_blk);
  k1_logits<<<dim3(N_ / 256, 4, B_), 512, 0, stream>>>(x, Wcomp, bcomp, w_blk, wt_blk);
  k2_S<<<dim3(8, NSPLIT, B_), 256, 0, stream>>>(wt_blk, xt_blk, S_p, norm);
  k2r<<<dim3(256), 256, 0, stream>>>(S_p, S);
  k3a_st<<<dim3(8, H_, B_), 256, 0, stream>>>(S, Wfx, bfx, norm, st);
  k3b_attn<<<dim3(H_, B_), 256, 0, stream>>>(st, Wq, Wk, Wv, os);
  k3c_ct<<<dim3(64, B_), 256, 0, stream>>>(os, Wout, Ct_blk);
  k4_out<<<dim3(DIN_ / 128, N_ / 128, B_), 256, 0, stream>>>(w_blk, Ct_blk, bout, out);
}